// Round 1
// baseline (713.396 us; speedup 1.0000x reference)
//
#include <hip/hip_runtime.h>

// ---------------------------------------------------------------------------
// GGNN: 2x GatedGraphConv(GRUCell) + linear + softmax-attention pooling.
// N=100000 nodes, E=1600000 edges, D=64.
//
// Algebraic fold: segment_sum((h@C)[src]) == (segment_sum(h[src]))@C,
// and agg@W_ih^T == s@(C@W_ih^T) =: s@F.  So per layer we only gather raw
// h-rows (CSR by dst, atomic-free) and run one fused dual-matvec GRU kernel.
// ---------------------------------------------------------------------------

__device__ __forceinline__ int wave_incl_scan(int v, int lane) {
#pragma unroll
  for (int d = 1; d < 64; d <<= 1) {
    int u = __shfl_up(v, d);
    if (lane >= d) v += u;
  }
  return v;
}

// Edge list may arrive as int32 or as int64 (we read low dwords). Runtime probe.
__device__ __forceinline__ void load_edge(const int* ei, int E, int is64,
                                          int e, int& s, int& d) {
  if (is64) { s = ei[2 * e]; d = ei[2 * (E + e)]; }
  else      { s = ei[e];     d = ei[E + e]; }
}

__global__ void detect_kernel(const int* __restrict__ ei, int* __restrict__ flag) {
  __shared__ int anynz;
  if (threadIdx.x == 0) anynz = 0;
  __syncthreads();
  for (int i = threadIdx.x; i < 512; i += blockDim.x)
    if (ei[2 * i + 1] != 0) anynz = 1;   // int64 layout => high dwords all 0
  __syncthreads();
  if (threadIdx.x == 0) *flag = (anynz == 0) ? 1 : 0;
}

__global__ void hist_kernel(const int* __restrict__ ei, int E,
                            const int* __restrict__ flag, int* __restrict__ counts) {
  int e = blockIdx.x * blockDim.x + threadIdx.x;
  if (e >= E) return;
  int is64 = *flag;
  int s, d; load_edge(ei, E, is64, e, s, d);
  atomicAdd(&counts[d], 1);
}

__global__ void scan_k1(const int* __restrict__ counts, int* __restrict__ row_ptr,
                        int* __restrict__ bsums, int N) {
  __shared__ int wsum[16];
  int tid = threadIdx.x, lane = tid & 63, wv = tid >> 6;
  int i = blockIdx.x * 1024 + tid;
  int v = (i < N) ? counts[i] : 0;
  int incl = wave_incl_scan(v, lane);
  if (lane == 63) wsum[wv] = incl;
  __syncthreads();
  if (wv == 0) {
    int x = (lane < 16) ? wsum[lane] : 0;
    int xi = wave_incl_scan(x, lane);
    if (lane < 16) wsum[lane] = xi - x;  // exclusive wave offsets
  }
  __syncthreads();
  incl += wsum[wv];
  if (i < N) row_ptr[i + 1] = incl;
  if (tid == 1023) bsums[blockIdx.x] = incl;
}

__global__ void scan_k2(int* __restrict__ bs, int nb) {
  int lane = threadIdx.x;  // 64 threads
  int running = 0;
  for (int base = 0; base < nb; base += 64) {
    int idx = base + lane;
    int v = (idx < nb) ? bs[idx] : 0;
    int incl = wave_incl_scan(v, lane);
    int total = __shfl(incl, 63);
    if (idx < nb) bs[idx] = running + incl - v;  // exclusive
    running += total;
  }
}

__global__ void scan_k3(int* __restrict__ row_ptr, const int* __restrict__ counts,
                        const int* __restrict__ bsums, int* __restrict__ cursor, int N) {
  int i = blockIdx.x * 1024 + threadIdx.x;
  if (blockIdx.x == 0 && threadIdx.x == 0) row_ptr[0] = 0;
  if (i < N) {
    int rp = row_ptr[i + 1] + bsums[blockIdx.x];
    row_ptr[i + 1] = rp;
    cursor[i] = rp - counts[i];
  }
}

__global__ void fill_kernel(const int* __restrict__ ei, int E,
                            const int* __restrict__ flag, int* __restrict__ cursor,
                            int* __restrict__ col) {
  int e = blockIdx.x * blockDim.x + threadIdx.x;
  if (e >= E) return;
  int is64 = *flag;
  int s, d; load_edge(ei, E, is64, e, s, d);
  int pos = atomicAdd(&cursor[d], 1);
  col[pos] = s;
}

// Fg[l][j][p] = sum_k conv_w[l][p][k] * w_ih[j][k]   (l in [0,2), j in [0,192), p in [0,64))
__global__ void fuse_kernel(const float* __restrict__ conv_w,
                            const float* __restrict__ w_ih, float* __restrict__ Fg) {
  int idx = blockIdx.x * blockDim.x + threadIdx.x;
  if (idx >= 2 * 192 * 64) return;
  int l = idx / (192 * 64);
  int r = idx % (192 * 64);
  int j = r >> 6, p = r & 63;
  const float* C = conv_w + l * 4096 + p * 64;
  const float* W = w_ih + j * 64;
  float acc = 0.f;
#pragma unroll 8
  for (int k = 0; k < 64; k++) acc += C[k] * W[k];
  Fg[idx] = acc;
}

// s[n,:] = sum over in-edges of h[src,:]   (one wave per node, lane = channel)
__global__ void gather_kernel(const float* __restrict__ hsrc,
                              const int* __restrict__ row_ptr,
                              const int* __restrict__ col,
                              float* __restrict__ sout, int N) {
  int gt = blockIdx.x * blockDim.x + threadIdx.x;
  int n = gt >> 6, c = gt & 63;
  if (n >= N) return;
  int beg = row_ptr[n], end = row_ptr[n + 1];
  float a0 = 0.f, a1 = 0.f, a2 = 0.f, a3 = 0.f;
  int e = beg;
  for (; e + 4 <= end; e += 4) {
    int p0 = col[e], p1 = col[e + 1], p2 = col[e + 2], p3 = col[e + 3];
    a0 += hsrc[(size_t)p0 * 64 + c];
    a1 += hsrc[(size_t)p1 * 64 + c];
    a2 += hsrc[(size_t)p2 * 64 + c];
    a3 += hsrc[(size_t)p3 * 64 + c];
  }
  for (; e < end; e++) a0 += hsrc[(size_t)col[e] * 64 + c];
  sout[(size_t)n * 64 + c] = (a0 + a1) + (a2 + a3);
}

// Fused dual matvec + GRU gates. 32 nodes/block, 4 waves, 8 nodes/wave.
// LDS: weights [192][68] (pad 68 -> conflict-free b128 column reads), s/h tiles.
__global__ __launch_bounds__(256) void gru_kernel(
    const float* __restrict__ s, const float* __restrict__ hin,
    float* __restrict__ hout, const float* __restrict__ Fg,
    const float* __restrict__ whh, const float* __restrict__ b_ih,
    const float* __restrict__ b_hh, int N) {
  extern __shared__ float lds[];
  float* wlds = lds;                // [192][68]
  float* s_lds = wlds + 192 * 68;   // [32][64]
  float* h_lds = s_lds + 32 * 64;   // [32][64]
  const int tid = threadIdx.x;
  const int c = tid & 63;
  const int wv = tid >> 6;
  const int n0 = blockIdx.x * 32;

  for (int i = tid; i < 512; i += 256) {       // 512 float4 per tile
    int base = i * 4, m = base >> 6, k = base & 63;
    int g = n0 + m;
    float4 sv = make_float4(0, 0, 0, 0), hv = make_float4(0, 0, 0, 0);
    if (g < N) {
      sv = *(const float4*)(s + (size_t)g * 64 + k);
      hv = *(const float4*)(hin + (size_t)g * 64 + k);
    }
    *(float4*)&s_lds[m * 64 + k] = sv;
    *(float4*)&h_lds[m * 64 + k] = hv;
  }
  for (int i = tid; i < 3072; i += 256) {      // F: 192x64 floats
    int j = i >> 4, p = (i & 15) * 4;
    *(float4*)&wlds[j * 68 + p] = *(const float4*)(Fg + j * 64 + p);
  }
  __syncthreads();

  float a0[8], a1[8], a2[8];
#pragma unroll
  for (int i = 0; i < 8; i++) { a0[i] = 0.f; a1[i] = 0.f; a2[i] = 0.f; }
#pragma unroll 4
  for (int k0 = 0; k0 < 64; k0 += 4) {
    float4 wr = *(const float4*)&wlds[c * 68 + k0];
    float4 wz = *(const float4*)&wlds[(64 + c) * 68 + k0];
    float4 wn = *(const float4*)&wlds[(128 + c) * 68 + k0];
#pragma unroll
    for (int i = 0; i < 8; i++) {
      float4 sv = *(const float4*)&s_lds[(wv * 8 + i) * 64 + k0];
      a0[i] += sv.x * wr.x + sv.y * wr.y + sv.z * wr.z + sv.w * wr.w;
      a1[i] += sv.x * wz.x + sv.y * wz.y + sv.z * wz.z + sv.w * wz.w;
      a2[i] += sv.x * wn.x + sv.y * wn.y + sv.z * wn.z + sv.w * wn.w;
    }
  }
  __syncthreads();
  for (int i = tid; i < 3072; i += 256) {      // W_hh: 192x64 floats (row-major already W[j][k])
    int j = i >> 4, p = (i & 15) * 4;
    *(float4*)&wlds[j * 68 + p] = *(const float4*)(whh + j * 64 + p);
  }
  __syncthreads();

  float g0[8], g1[8], g2[8];
#pragma unroll
  for (int i = 0; i < 8; i++) { g0[i] = 0.f; g1[i] = 0.f; g2[i] = 0.f; }
#pragma unroll 4
  for (int k0 = 0; k0 < 64; k0 += 4) {
    float4 wr = *(const float4*)&wlds[c * 68 + k0];
    float4 wz = *(const float4*)&wlds[(64 + c) * 68 + k0];
    float4 wn = *(const float4*)&wlds[(128 + c) * 68 + k0];
#pragma unroll
    for (int i = 0; i < 8; i++) {
      float4 hv = *(const float4*)&h_lds[(wv * 8 + i) * 64 + k0];
      g0[i] += hv.x * wr.x + hv.y * wr.y + hv.z * wr.z + hv.w * wr.w;
      g1[i] += hv.x * wz.x + hv.y * wz.y + hv.z * wz.z + hv.w * wz.w;
      g2[i] += hv.x * wn.x + hv.y * wn.y + hv.z * wn.z + hv.w * wn.w;
    }
  }

  float bir = b_ih[c], biz = b_ih[64 + c], bin_ = b_ih[128 + c];
  float bhr = b_hh[c], bhz = b_hh[64 + c], bhn = b_hh[128 + c];
#pragma unroll
  for (int i = 0; i < 8; i++) {
    int g = n0 + wv * 8 + i;
    if (g >= N) continue;
    float rr = 1.f / (1.f + __expf(-((a0[i] + bir) + (g0[i] + bhr))));
    float zz = 1.f / (1.f + __expf(-((a1[i] + biz) + (g1[i] + bhz))));
    float narg = (a2[i] + bin_) + rr * (g2[i] + bhn);
    narg = fminf(fmaxf(narg, -15.f), 15.f);
    float t = __expf(2.f * narg);
    float nn = (t - 1.f) / (t + 1.f);
    float hold = h_lds[(wv * 8 + i) * 64 + c];
    hout[(size_t)g * 64 + c] = (1.f - zz) * nn + zz * hold;
  }
}

// Readout: y = relu(h)@lin_w^T + lin_b; t = y.attn_w + attn_b; partial
// sums of exp(t) and exp(t)*y per block. |t| is O(1) so no max-subtraction.
__global__ __launch_bounds__(256) void final_p1(
    const float* __restrict__ h, const float* __restrict__ lin_w,
    const float* __restrict__ lin_b, const float* __restrict__ attn_w,
    const float* __restrict__ attn_b, float* __restrict__ partials, int N) {
  __shared__ float wl[64 * 68];
  __shared__ float redY[4][64];
  __shared__ float redS[4];
  int tid = threadIdx.x, j = tid & 63, wv = tid >> 6;
  for (int i = tid; i < 1024; i += 256) {
    int r = i >> 4, p = (i & 15) * 4;
    *(float4*)&wl[r * 68 + p] = *(const float4*)(lin_w + r * 64 + p);
  }
  float aw = attn_w[j];
  float bl = lin_b[j];
  float ab = attn_b[0];
  __syncthreads();
  float accY = 0.f, accS = 0.f;
  int stride = gridDim.x * 4;
  for (int n = blockIdx.x * 4 + wv; n < N; n += stride) {
    float hv = h[(size_t)n * 64 + j];
    float hr = fmaxf(hv, 0.f);
    float y = bl;
#pragma unroll
    for (int k0 = 0; k0 < 64; k0 += 4) {
      float4 w4 = *(const float4*)&wl[j * 68 + k0];
      y += __shfl(hr, k0) * w4.x + __shfl(hr, k0 + 1) * w4.y +
           __shfl(hr, k0 + 2) * w4.z + __shfl(hr, k0 + 3) * w4.w;
    }
    float tv = y * aw;
#pragma unroll
    for (int off = 32; off > 0; off >>= 1) tv += __shfl_xor(tv, off);
    tv += ab;
    float p = __expf(tv);
    accY += p * y;
    accS += p;
  }
  redY[wv][j] = accY;
  if (j == 0) redS[wv] = accS;
  __syncthreads();
  if (wv == 0) {
    float t = redY[0][j] + redY[1][j] + redY[2][j] + redY[3][j];
    partials[blockIdx.x * 66 + j] = t;
    if (j == 0)
      partials[blockIdx.x * 66 + 64] = redS[0] + redS[1] + redS[2] + redS[3];
  }
}

__global__ void final_p2(const float* __restrict__ partials,
                         float* __restrict__ out, int nb) {
  __shared__ float red[16][65];
  int tid = threadIdx.x;  // 1024
  int j = tid & 63, grp = tid >> 6;
  float sy = 0.f, ss = 0.f;
  for (int b = grp; b < nb; b += 16) {
    sy += partials[b * 66 + j];
    if (j == 0) ss += partials[b * 66 + 64];
  }
  red[grp][j] = sy;
  if (j == 0) red[grp][64] = ss;
  __syncthreads();
  if (tid < 64) {
    float Y = 0.f, S = 0.f;
#pragma unroll
    for (int i = 0; i < 16; i++) { Y += red[i][tid]; S += red[i][64]; }
    out[tid] = Y / S;
  }
}

extern "C" void kernel_launch(void* const* d_in, const int* in_sizes, int n_in,
                              void* d_out, int out_size, void* d_ws, size_t ws_size,
                              hipStream_t stream) {
  const float* x       = (const float*)d_in[0];
  const int*   ei      = (const int*)d_in[1];
  const float* conv_w  = (const float*)d_in[2];
  const float* gw_ih   = (const float*)d_in[3];
  const float* gw_hh   = (const float*)d_in[4];
  const float* gb_ih   = (const float*)d_in[5];
  const float* gb_hh   = (const float*)d_in[6];
  const float* lin_w   = (const float*)d_in[7];
  const float* lin_b   = (const float*)d_in[8];
  const float* attn_w  = (const float*)d_in[9];
  const float* attn_b  = (const float*)d_in[10];
  float* out = (float*)d_out;

  const int N = in_sizes[0] / 64;
  const int E = in_sizes[1] / 2;

  char* ws = (char*)d_ws;
  size_t off = 0;
  auto alloc = [&](size_t bytes) {
    void* p = ws + off;
    off = (off + bytes + 255) & ~(size_t)255;
    return p;
  };
  int*   counts   = (int*)alloc((size_t)N * 4);
  int*   row_ptr  = (int*)alloc((size_t)(N + 1) * 4);
  int*   cursor   = (int*)alloc((size_t)N * 4);
  int*   colb     = (int*)alloc((size_t)E * 4);
  int*   bsums    = (int*)alloc(4096);
  int*   flag     = (int*)alloc(256);
  float* Fg       = (float*)alloc(2 * 192 * 64 * 4);
  float* sbuf     = (float*)alloc((size_t)N * 64 * 4);
  float* hbuf     = (float*)alloc((size_t)N * 64 * 4);
  float* partials = (float*)alloc(1024 * 66 * 4);
  if (off > ws_size) return;  // ws too small: leave output poisoned (visible failure)

  hipMemsetAsync(counts, 0, (size_t)N * 4, stream);
  detect_kernel<<<1, 256, 0, stream>>>(ei, flag);
  int eb = (E + 255) / 256;
  hist_kernel<<<eb, 256, 0, stream>>>(ei, E, flag, counts);
  int nb = (N + 1023) / 1024;
  scan_k1<<<nb, 1024, 0, stream>>>(counts, row_ptr, bsums, N);
  scan_k2<<<1, 64, 0, stream>>>(bsums, nb);
  scan_k3<<<nb, 1024, 0, stream>>>(row_ptr, counts, bsums, cursor, N);
  fill_kernel<<<eb, 256, 0, stream>>>(ei, E, flag, cursor, colb);
  fuse_kernel<<<(2 * 192 * 64 + 255) / 256, 256, 0, stream>>>(conv_w, gw_ih, Fg);

  size_t shmem = (size_t)(192 * 68 + 32 * 64 + 32 * 64) * sizeof(float);  // 68608 B
  hipFuncSetAttribute((const void*)gru_kernel,
                      hipFuncAttributeMaxDynamicSharedMemorySize, (int)shmem);
  int gb = (N * 64 + 255) / 256;   // gather blocks (1 wave per node)
  int ub = (N + 31) / 32;          // gru blocks

  // layer 0 (h = x)
  gather_kernel<<<gb, 256, 0, stream>>>(x, row_ptr, colb, sbuf, N);
  gru_kernel<<<ub, 256, shmem, stream>>>(sbuf, x, hbuf, Fg, gw_hh, gb_ih, gb_hh, N);
  // layer 1 (in-place h update is safe: gather consumed h first, rows disjoint)
  gather_kernel<<<gb, 256, 0, stream>>>(hbuf, row_ptr, colb, sbuf, N);
  gru_kernel<<<ub, 256, shmem, stream>>>(sbuf, hbuf, hbuf, Fg + 192 * 64, gw_hh,
                                         gb_ih, gb_hh, N);
  // readout
  final_p1<<<1024, 256, 0, stream>>>(hbuf, lin_w, lin_b, attn_w, attn_b, partials, N);
  final_p2<<<1, 1024, 0, stream>>>(partials, out, 1024);
}

// Round 2
// 530.084 us; speedup vs baseline: 1.3458x; 1.3458x over previous
//
#include <hip/hip_runtime.h>

// ---------------------------------------------------------------------------
// GGNN: 2x GatedGraphConv(GRUCell) + linear + softmax-attention pooling.
// N=100000 nodes, E=1600000 edges, D=64.
//
// Folds: segment_sum((h@C)[src]) == (segment_sum(h[src]))@C, and
// agg@W_ih^T == s@(C@W_ih^T).  Per layer: gather raw h rows (CSR by dst),
// then ONE fused GEMM  [N x 128 (s||h)] @ [128 x 256 (r|z|i_n|h_n)]  done
// with MFMA bf16 3-term emulation (Ah Bh + Ah Bl + Al Bh ~ f32 accuracy),
// GRU gate math fused in-register in the epilogue.
// ---------------------------------------------------------------------------

typedef __attribute__((ext_vector_type(8))) short s8v;    // 8 bf16 (4 VGPRs)
typedef __attribute__((ext_vector_type(4))) float f32x4;  // MFMA accumulator

__device__ __forceinline__ unsigned short f32_bf16_rn(float x) {
  unsigned u = __float_as_uint(x);
  u += 0x7FFF + ((u >> 16) & 1);
  return (unsigned short)(u >> 16);
}

__device__ __forceinline__ int wave_incl_scan(int v, int lane) {
#pragma unroll
  for (int d = 1; d < 64; d <<= 1) {
    int u = __shfl_up(v, d);
    if (lane >= d) v += u;
  }
  return v;
}

// Edge list may arrive as int32 or as int64 (we read low dwords). Runtime probe.
__device__ __forceinline__ void load_edge(const int* ei, int E, int is64,
                                          int e, int& s, int& d) {
  if (is64) { s = ei[2 * e]; d = ei[2 * (E + e)]; }
  else      { s = ei[e];     d = ei[E + e]; }
}

__global__ void detect_kernel(const int* __restrict__ ei, int* __restrict__ flag) {
  __shared__ int anynz;
  if (threadIdx.x == 0) anynz = 0;
  __syncthreads();
  for (int i = threadIdx.x; i < 512; i += blockDim.x)
    if (ei[2 * i + 1] != 0) anynz = 1;   // int64 layout => high dwords all 0
  __syncthreads();
  if (threadIdx.x == 0) *flag = (anynz == 0) ? 1 : 0;
}

__global__ void hist_kernel(const int* __restrict__ ei, int E,
                            const int* __restrict__ flag, int* __restrict__ counts) {
  int e = blockIdx.x * blockDim.x + threadIdx.x;
  if (e >= E) return;
  int is64 = *flag;
  int s, d; load_edge(ei, E, is64, e, s, d);
  atomicAdd(&counts[d], 1);
}

__global__ void scan_k1(const int* __restrict__ counts, int* __restrict__ row_ptr,
                        int* __restrict__ bsums, int N) {
  __shared__ int wsum[16];
  int tid = threadIdx.x, lane = tid & 63, wv = tid >> 6;
  int i = blockIdx.x * 1024 + tid;
  int v = (i < N) ? counts[i] : 0;
  int incl = wave_incl_scan(v, lane);
  if (lane == 63) wsum[wv] = incl;
  __syncthreads();
  if (wv == 0) {
    int x = (lane < 16) ? wsum[lane] : 0;
    int xi = wave_incl_scan(x, lane);
    if (lane < 16) wsum[lane] = xi - x;  // exclusive wave offsets
  }
  __syncthreads();
  incl += wsum[wv];
  if (i < N) row_ptr[i + 1] = incl;
  if (tid == 1023) bsums[blockIdx.x] = incl;
}

__global__ void scan_k2(int* __restrict__ bs, int nb) {
  int lane = threadIdx.x;  // 64 threads
  int running = 0;
  for (int base = 0; base < nb; base += 64) {
    int idx = base + lane;
    int v = (idx < nb) ? bs[idx] : 0;
    int incl = wave_incl_scan(v, lane);
    int total = __shfl(incl, 63);
    if (idx < nb) bs[idx] = running + incl - v;  // exclusive
    running += total;
  }
}

__global__ void scan_k3(int* __restrict__ row_ptr, const int* __restrict__ counts,
                        const int* __restrict__ bsums, int* __restrict__ cursor, int N) {
  int i = blockIdx.x * 1024 + threadIdx.x;
  if (blockIdx.x == 0 && threadIdx.x == 0) row_ptr[0] = 0;
  if (i < N) {
    int rp = row_ptr[i + 1] + bsums[blockIdx.x];
    row_ptr[i + 1] = rp;
    cursor[i] = rp - counts[i];
  }
}

__global__ void fill_kernel(const int* __restrict__ ei, int E,
                            const int* __restrict__ flag, int* __restrict__ cursor,
                            int* __restrict__ col) {
  int e = blockIdx.x * blockDim.x + threadIdx.x;
  if (e >= E) return;
  int is64 = *flag;
  int s, d; load_edge(ei, E, is64, e, s, d);
  int pos = atomicAdd(&cursor[d], 1);
  col[pos] = s;
}

// Fg[l][j][p] = sum_k conv_w[l][p][k] * w_ih[j][k]
__global__ void fuse_kernel(const float* __restrict__ conv_w,
                            const float* __restrict__ w_ih, float* __restrict__ Fg) {
  int idx = blockIdx.x * blockDim.x + threadIdx.x;
  if (idx >= 2 * 192 * 64) return;
  int l = idx / (192 * 64);
  int r = idx % (192 * 64);
  int j = r >> 6, p = r & 63;
  const float* C = conv_w + l * 4096 + p * 64;
  const float* W = w_ih + j * 64;
  float acc = 0.f;
#pragma unroll 8
  for (int k = 0; k < 64; k++) acc += C[k] * W[k];
  Fg[idx] = acc;
}

// Build transposed, hi/lo-split B for the fused GEMM.
// Logical B[p][c] (p=K in [0,128), c=col in [0,256)):
//   gate g=c>>6, channel ch=c&63
//   p<64  (s side): g0->Fg[ch][p]  g1->Fg[64+ch][p]  g2->Fg[128+ch][p]  g3->0
//   p>=64 (h side): g0->Whh[ch][q] g1->Whh[64+ch][q] g2->0  g3->Whh[128+ch][q]
// Stored as Bt[l][term][c][p] bf16, term0=hi, term1=lo.
__global__ void bt_kernel(const float* __restrict__ Fg,
                          const float* __restrict__ whh,
                          unsigned short* __restrict__ Bt) {
  int idx = blockIdx.x * blockDim.x + threadIdx.x;
  if (idx >= 2 * 256 * 128) return;
  int l = idx >> 15;
  int rr = idx & 32767;
  int c = rr >> 7, p = rr & 127;
  int g = c >> 6, ch = c & 63;
  float val = 0.f;
  if (p < 64) {
    if (g == 0)      val = Fg[(size_t)l * 12288 + ch * 64 + p];
    else if (g == 1) val = Fg[(size_t)l * 12288 + (64 + ch) * 64 + p];
    else if (g == 2) val = Fg[(size_t)l * 12288 + (128 + ch) * 64 + p];
  } else {
    int q = p - 64;
    if (g == 0)      val = whh[ch * 64 + q];
    else if (g == 1) val = whh[(64 + ch) * 64 + q];
    else if (g == 3) val = whh[(128 + ch) * 64 + q];
  }
  unsigned short hi = f32_bf16_rn(val);
  float fh = __uint_as_float((unsigned)hi << 16);
  unsigned short lo = f32_bf16_rn(val - fh);
  size_t base = (size_t)l * 65536;
  Bt[base + (size_t)c * 128 + p] = hi;
  Bt[base + 32768 + (size_t)c * 128 + p] = lo;
}

// s[n,:] = sum over in-edges of h[src,:]   (one wave per node, lane = channel)
__global__ void gather_kernel(const float* __restrict__ hsrc,
                              const int* __restrict__ row_ptr,
                              const int* __restrict__ col,
                              float* __restrict__ sout, int N) {
  int gt = blockIdx.x * blockDim.x + threadIdx.x;
  int n = gt >> 6, c = gt & 63;
  if (n >= N) return;
  int beg = row_ptr[n], end = row_ptr[n + 1];
  float a0 = 0.f, a1 = 0.f, a2 = 0.f, a3 = 0.f;
  int e = beg;
  for (; e + 4 <= end; e += 4) {
    int p0 = col[e], p1 = col[e + 1], p2 = col[e + 2], p3 = col[e + 3];
    a0 += hsrc[(size_t)p0 * 64 + c];
    a1 += hsrc[(size_t)p1 * 64 + c];
    a2 += hsrc[(size_t)p2 * 64 + c];
    a3 += hsrc[(size_t)p3 * 64 + c];
  }
  for (; e < end; e++) a0 += hsrc[(size_t)col[e] * 64 + c];
  sout[(size_t)n * 64 + c] = (a0 + a1) + (a2 + a3);
}

// Fused MFMA GEMM + GRU gates. Block = 4 waves; wave w owns channels
// [16w,16w+16) of ALL four gates -> B fragments live in 128 VGPRs for the
// whole kernel and gate math is in-register. A-tile (64 nodes x 128 (s||h),
// hi+lo bf16) staged in LDS with +8-short pad (bank-uniform ds_read_b128).
__global__ __launch_bounds__(256, 2) void gemm_gru_kernel(
    const float* __restrict__ sb, const float* __restrict__ hin,
    float* __restrict__ hout, const unsigned short* __restrict__ bt,
    const float* __restrict__ b_ih, const float* __restrict__ b_hh,
    int N, int ntiles) {
  __shared__ short Alds[2 * 64 * 136];   // hi matrix then lo matrix
  const int tid = threadIdx.x;
  const int lane = tid & 63, w = tid >> 6;
  const int l15 = lane & 15, ko = (lane >> 4) * 8;

  // Resident B fragments: [gate][kstep], hi and lo.
  s8v Bh[4][4], Bl[4][4];
  {
    const int col = 16 * w + l15;
#pragma unroll
    for (int c = 0; c < 4; c++)
#pragma unroll
      for (int kk = 0; kk < 4; kk++) {
        size_t o = (size_t)(64 * c + col) * 128 + kk * 32 + ko;
        Bh[c][kk] = *(const s8v*)(bt + o);
        Bl[c][kk] = *(const s8v*)(bt + 32768 + o);
      }
  }
  const int ch = 16 * w + l15;
  const float br = b_ih[ch] + b_hh[ch];
  const float bz = b_ih[64 + ch] + b_hh[64 + ch];
  const float bin_ = b_ih[128 + ch];
  const float bhn = b_hh[128 + ch];
  const int q4 = (lane >> 4) * 4;
  const int sr = tid >> 2, part = tid & 3;   // staging: row 0..63, k-quarter

  for (int tile = blockIdx.x; tile < ntiles; tile += gridDim.x) {
    const int nb = tile * 64;
    {  // ---- stage A = [s || h] as bf16 hi/lo ----
      int node = nb + sr;
      f32x4 v[8];
      if (node < N) {
        const float* base = (part < 2) ? (sb + (size_t)node * 64 + part * 32)
                                       : (hin + (size_t)node * 64 + (part - 2) * 32);
#pragma unroll
        for (int i = 0; i < 8; i++) v[i] = *(const f32x4*)(base + 4 * i);
      } else {
#pragma unroll
        for (int i = 0; i < 8; i++) v[i] = (f32x4)(0.f);
      }
      short* ah = &Alds[sr * 136 + part * 32];
#pragma unroll
      for (int i2 = 0; i2 < 4; i2++) {
        s8v hv, lv;
#pragma unroll
        for (int e = 0; e < 8; e++) {
          float x = v[i2 * 2 + (e >> 2)][e & 3];
          unsigned short hb = f32_bf16_rn(x);
          float fh = __uint_as_float((unsigned)hb << 16);
          unsigned short lb = f32_bf16_rn(x - fh);
          hv[e] = (short)hb;
          lv[e] = (short)lb;
        }
        *(s8v*)(ah + i2 * 8) = hv;
        *(s8v*)(ah + 64 * 136 + i2 * 8) = lv;
      }
    }
    __syncthreads();

    f32x4 acc[4][4];
#pragma unroll
    for (int m = 0; m < 4; m++)
#pragma unroll
      for (int c = 0; c < 4; c++) acc[m][c] = (f32x4)(0.f);

#pragma unroll
    for (int m = 0; m < 4; m++) {
      const short* arow = &Alds[(16 * m + l15) * 136 + ko];
#pragma unroll
      for (int kk = 0; kk < 4; kk++) {
        s8v a_h = *(const s8v*)(arow + kk * 32);
        s8v a_l = *(const s8v*)(arow + 64 * 136 + kk * 32);
#pragma unroll
        for (int c = 0; c < 4; c++) {
          acc[m][c] = __builtin_amdgcn_mfma_f32_16x16x32_bf16(a_h, Bh[c][kk], acc[m][c], 0, 0, 0);
          acc[m][c] = __builtin_amdgcn_mfma_f32_16x16x32_bf16(a_h, Bl[c][kk], acc[m][c], 0, 0, 0);
          acc[m][c] = __builtin_amdgcn_mfma_f32_16x16x32_bf16(a_l, Bh[c][kk], acc[m][c], 0, 0, 0);
        }
      }
    }
    __syncthreads();  // protect LDS before next tile's staging

    // ---- GRU gate epilogue (fully in-register) ----
#pragma unroll
    for (int m = 0; m < 4; m++) {
#pragma unroll
      for (int g = 0; g < 4; g++) {
        int node = nb + 16 * m + q4 + g;
        if (node < N) {
          float hold = hin[(size_t)node * 64 + ch];
          float rr = 1.f / (1.f + __expf(-(acc[m][0][g] + br)));
          float zz = 1.f / (1.f + __expf(-(acc[m][1][g] + bz)));
          float narg = acc[m][2][g] + bin_ + rr * (acc[m][3][g] + bhn);
          narg = fminf(fmaxf(narg, -15.f), 15.f);
          float t = __expf(2.f * narg);
          float nn = (t - 1.f) / (t + 1.f);
          hout[(size_t)node * 64 + ch] = (1.f - zz) * nn + zz * hold;
        }
      }
    }
  }
}

// Readout: y = relu(h)@lin_w^T + lin_b; t = y.attn_w + attn_b; partial
// sums of exp(t) and exp(t)*y per block. |t| is O(1) so no max-subtraction.
__global__ __launch_bounds__(256) void final_p1(
    const float* __restrict__ h, const float* __restrict__ lin_w,
    const float* __restrict__ lin_b, const float* __restrict__ attn_w,
    const float* __restrict__ attn_b, float* __restrict__ partials, int N) {
  __shared__ float wl[64 * 68];
  __shared__ float redY[4][64];
  __shared__ float redS[4];
  int tid = threadIdx.x, j = tid & 63, wv = tid >> 6;
  for (int i = tid; i < 1024; i += 256) {
    int r = i >> 4, p = (i & 15) * 4;
    *(float4*)&wl[r * 68 + p] = *(const float4*)(lin_w + r * 64 + p);
  }
  float aw = attn_w[j];
  float bl = lin_b[j];
  float ab = attn_b[0];
  __syncthreads();
  float accY = 0.f, accS = 0.f;
  int stride = gridDim.x * 4;
  for (int n = blockIdx.x * 4 + wv; n < N; n += stride) {
    float hv = h[(size_t)n * 64 + j];
    float hr = fmaxf(hv, 0.f);
    float y = bl;
#pragma unroll
    for (int k0 = 0; k0 < 64; k0 += 4) {
      float4 w4 = *(const float4*)&wl[j * 68 + k0];
      y += __shfl(hr, k0) * w4.x + __shfl(hr, k0 + 1) * w4.y +
           __shfl(hr, k0 + 2) * w4.z + __shfl(hr, k0 + 3) * w4.w;
    }
    float tv = y * aw;
#pragma unroll
    for (int off = 32; off > 0; off >>= 1) tv += __shfl_xor(tv, off);
    tv += ab;
    float p = __expf(tv);
    accY += p * y;
    accS += p;
  }
  redY[wv][j] = accY;
  if (j == 0) redS[wv] = accS;
  __syncthreads();
  if (wv == 0) {
    float t = redY[0][j] + redY[1][j] + redY[2][j] + redY[3][j];
    partials[blockIdx.x * 66 + j] = t;
    if (j == 0)
      partials[blockIdx.x * 66 + 64] = redS[0] + redS[1] + redS[2] + redS[3];
  }
}

__global__ void final_p2(const float* __restrict__ partials,
                         float* __restrict__ out, int nb) {
  __shared__ float red[16][65];
  int tid = threadIdx.x;  // 1024
  int j = tid & 63, grp = tid >> 6;
  float sy = 0.f, ss = 0.f;
  for (int b = grp; b < nb; b += 16) {
    sy += partials[b * 66 + j];
    if (j == 0) ss += partials[b * 66 + 64];
  }
  red[grp][j] = sy;
  if (j == 0) red[grp][64] = ss;
  __syncthreads();
  if (tid < 64) {
    float Y = 0.f, S = 0.f;
#pragma unroll
    for (int i = 0; i < 16; i++) { Y += red[i][tid]; S += red[i][64]; }
    out[tid] = Y / S;
  }
}

extern "C" void kernel_launch(void* const* d_in, const int* in_sizes, int n_in,
                              void* d_out, int out_size, void* d_ws, size_t ws_size,
                              hipStream_t stream) {
  const float* x       = (const float*)d_in[0];
  const int*   ei      = (const int*)d_in[1];
  const float* conv_w  = (const float*)d_in[2];
  const float* gw_ih   = (const float*)d_in[3];
  const float* gw_hh   = (const float*)d_in[4];
  const float* gb_ih   = (const float*)d_in[5];
  const float* gb_hh   = (const float*)d_in[6];
  const float* lin_w   = (const float*)d_in[7];
  const float* lin_b   = (const float*)d_in[8];
  const float* attn_w  = (const float*)d_in[9];
  const float* attn_b  = (const float*)d_in[10];
  float* out = (float*)d_out;

  const int N = in_sizes[0] / 64;
  const int E = in_sizes[1] / 2;

  char* ws = (char*)d_ws;
  size_t off = 0;
  auto alloc = [&](size_t bytes) {
    void* p = ws + off;
    off = (off + bytes + 255) & ~(size_t)255;
    return p;
  };
  int*   counts   = (int*)alloc((size_t)N * 4);
  int*   row_ptr  = (int*)alloc((size_t)(N + 1) * 4);
  int*   cursor   = (int*)alloc((size_t)N * 4);
  int*   colb     = (int*)alloc((size_t)E * 4);
  int*   bsums    = (int*)alloc(4096);
  int*   flag     = (int*)alloc(256);
  float* Fg       = (float*)alloc(2 * 192 * 64 * 4);
  unsigned short* Bt = (unsigned short*)alloc(2 * 2 * 256 * 128 * 2);
  float* sbuf     = (float*)alloc((size_t)N * 64 * 4);
  float* hbuf     = (float*)alloc((size_t)N * 64 * 4);
  float* partials = (float*)alloc(1024 * 66 * 4);
  if (off > ws_size) return;  // ws too small: leave output poisoned

  hipMemsetAsync(counts, 0, (size_t)N * 4, stream);
  detect_kernel<<<1, 256, 0, stream>>>(ei, flag);
  int eb = (E + 255) / 256;
  hist_kernel<<<eb, 256, 0, stream>>>(ei, E, flag, counts);
  int nb = (N + 1023) / 1024;
  scan_k1<<<nb, 1024, 0, stream>>>(counts, row_ptr, bsums, N);
  scan_k2<<<1, 64, 0, stream>>>(bsums, nb);
  scan_k3<<<nb, 1024, 0, stream>>>(row_ptr, counts, bsums, cursor, N);
  fill_kernel<<<eb, 256, 0, stream>>>(ei, E, flag, cursor, colb);
  fuse_kernel<<<(2 * 192 * 64 + 255) / 256, 256, 0, stream>>>(conv_w, gw_ih, Fg);
  bt_kernel<<<(2 * 256 * 128 + 255) / 256, 256, 0, stream>>>(Fg, gw_hh, Bt);

  int gb = (N * 64 + 255) / 256;       // gather: 1 wave per node
  int ntiles = (N + 63) / 64;
  // layer 0 (h = x)
  gather_kernel<<<gb, 256, 0, stream>>>(x, row_ptr, colb, sbuf, N);
  gemm_gru_kernel<<<512, 256, 0, stream>>>(sbuf, x, hbuf, Bt, gb_ih, gb_hh, N, ntiles);
  // layer 1 (in-place h update: each (node,ch) read+written by same thread)
  gather_kernel<<<gb, 256, 0, stream>>>(hbuf, row_ptr, colb, sbuf, N);
  gemm_gru_kernel<<<512, 256, 0, stream>>>(sbuf, hbuf, hbuf, Bt + 65536, gb_ih, gb_hh, N, ntiles);
  // readout
  final_p1<<<1024, 256, 0, stream>>>(hbuf, lin_w, lin_b, attn_w, attn_b, partials, N);
  final_p2<<<1, 1024, 0, stream>>>(partials, out, 1024);
}